// Round 11
// baseline (135.878 us; speedup 1.0000x reference)
//
#include <hip/hip_runtime.h>

#define NUM_EMB 1024
#define EMB_DIM 256
#define MARGIN 1e-3f

typedef __attribute__((ext_vector_type(8))) short short8v;
typedef __attribute__((ext_vector_type(4))) float f32x4;
typedef unsigned long long u64;
typedef unsigned int u32;

__device__ __forceinline__ u32 sortable(float f) {
    u32 u = __float_as_uint(f);
    return (u & 0x80000000u) ? ~u : (u | 0x80000000u);
}
__device__ __forceinline__ float unsortable(u32 s) {
    u32 u = (s & 0x80000000u) ? (s & 0x7FFFFFFFu) : ~s;
    return __uint_as_float(u);
}
__device__ __forceinline__ u64 umin64(u64 a, u64 b) { return a < b ? a : b; }

// RNE fp32 -> bf16 bits
__device__ __forceinline__ unsigned short f2bf(float f) {
    u32 u = __float_as_uint(f);
    u32 r = (u + 0x7FFFu + ((u >> 16) & 1u)) >> 16;
    return (unsigned short)r;
}
__device__ __forceinline__ float bf2f(unsigned short h) {
    return __uint_as_float(((u32)h) << 16);
}

#define GLP(p)  ((const __attribute__((address_space(1))) unsigned int*)(p))
#define LDSP(p) ((__attribute__((address_space(3))) unsigned int*)(p))

// ---- fused prep: role-split by blockIdx (r4/r7-proven logic, verbatim) ----
// bid 0..63: transpose E->ET; 64..65: normE; 66..97: eprep; 98..353: xprep (128-row tiles)
__global__ __launch_bounds__(512)
void vq_prep(const float* __restrict__ X, const float* __restrict__ E,
             float* __restrict__ ET, float* __restrict__ normE,
             char* __restrict__ Es, char* __restrict__ Xs) {
    __shared__ float tile[64][65];
    const int bid = blockIdx.x;
    const int t = threadIdx.x;
    if (bid < 64) {
        const int j0 = (bid & 15) * 64, d0 = (bid >> 4) * 64;
        const int tj = t & 63, td = t >> 6;
#pragma unroll
        for (int k = 0; k < 8; k++) {
            int dl = k * 8 + td;
            tile[dl][tj] = E[(d0 + dl) * NUM_EMB + j0 + tj];
        }
        __syncthreads();
        const int dd = t & 63, tw = t >> 6;
#pragma unroll
        for (int k = 0; k < 8; k++) {
            int jj = k * 8 + tw;
            ET[(j0 + jj) * EMB_DIM + d0 + dd] = tile[dd][jj];
        }
    } else if (bid < 66) {
        const int j = (bid - 64) * 512 + t;
        float s = 0.f;
#pragma unroll 8
        for (int d = 0; d < EMB_DIM; d++) {
            float v = E[d * NUM_EMB + j];
            s = fmaf(v, v, s);
        }
        normE[j] = s;
    } else if (bid < 98) {
        const int rb = bid - 66;                // 0..31
        const int nblk = rb >> 3, ks = rb & 7;
#pragma unroll
        for (int i = 0; i < 4; i++) {
            int gid = i * 512 + t;              // 256 cols x 8 k8-groups
            int col = gid >> 3;
            int k8 = gid & 7;
            int kg = ks * 64 + k8 * 8;
            int isLo = kg >= 256;
            int d0 = isLo ? kg - 256 : kg;
            int colg = nblk * 256 + col;
            short8v v;
#pragma unroll
            for (int j = 0; j < 8; j++) {
                float e = E[(d0 + j) * NUM_EMB + colg];
                unsigned short h = f2bf(e);
                if (isLo) h = f2bf(e - bf2f(h));
                v[j] = (short)h;
            }
            size_t off = (size_t)nblk * 262144 + (size_t)ks * 32768 +
                         (size_t)(((col * 128 + (k8 * 8) * 2) ^ ((col & 7) << 4)));
            *(short8v*)(Es + off) = v;
        }
    } else {
        const int mblk = bid - 98;              // 0..255 (128-row tiles)
#pragma unroll
        for (int i = 0; i < 8; i++) {
            int gid = i * 512 + t;              // 128 rows x 32 d8-groups
            int row = gid >> 5;
            int d0 = (gid & 31) * 8;
            const float4* xp4 = (const float4*)(X + ((size_t)mblk * 128 + row) * 256 + d0);
            float4 xa = xp4[0], xb = xp4[1];
            float xv[8] = {xa.x, xa.y, xa.z, xa.w, xb.x, xb.y, xb.z, xb.w};
            short8v vh, vl;
#pragma unroll
            for (int j = 0; j < 8; j++) {
                unsigned short h = f2bf(xv[j]);
                vh[j] = (short)h;
                vl[j] = (short)f2bf(xv[j] - bf2f(h));
            }
            int ksh = d0 >> 6, kl = d0 & 63;
            size_t inner = (size_t)(((row * 128 + kl * 2) ^ ((row & 7) << 4)));
            size_t base = (size_t)mblk * 131072;
            *(short8v*)(Xs + base + (size_t)ksh * 16384 + inner) = vh;
            *(short8v*)(Xs + base + (size_t)(ksh + 4) * 16384 + inner) = vl;
        }
    }
}

// ---- GEMM + per-block argmin/second-best ----
// r7 geometry: grid 1024 = 256 mblk x 4 nblk (XCD swizzle), 512 thr, BM=128 BN=256 BK=64
// r11: depth-2 pipeline. LDS 114688 = A ring 3x16K @0 + B ring 2x32K @49152.
//   step s: entry vmcnt(2) [keeps A(s+1) in flight; drains B(s), issued 1 step ago] ; barrier
//     phase0 (kk0): ds_read af/bf ; issue B(s+1) [early, T14] ; bar ; lgkm0 ; prio1 ; 16 MFMA ; prio0 ; bar
//     phase1 (kk1): ds_read af/bf ; issue A(s+2) ; bar ; lgkm0 ; prio1 ; 16 MFMA ; prio0
//   vmcnt never 0 mid-loop (T4); vmcnt(0) only at s=11.
// K=768: A ksteps {0,1,2,3,0,1,2,3,4,5,6,7}; B ksteps {0,1,2,3,4,5,6,7,0,1,2,3}
__global__ __launch_bounds__(512, 1)
void vq_gemm(const char* __restrict__ Xs, const char* __restrict__ Es,
             const float* __restrict__ normE,
             u64* __restrict__ gkey, float* __restrict__ gm2) {
    extern __shared__ char smem[];
    const int t = threadIdx.x;
    const int bid = blockIdx.x;
    const int lbid = (bid & 7) * 128 + (bid >> 3);
    const int mblk = lbid >> 2;
    const int nblk = lbid & 3;
    const int w = t >> 6, l = t & 63;
    const int wm = w >> 2, wn = w & 3;
    const int lr = l & 15, lg = l >> 4;
    const int swz = (l & 7) << 4;

    const char* Asrc = Xs + (size_t)mblk * 131072;
    const char* Bsrc = Es + (size_t)nblk * 262144;

    const int aB = (wm * 64 + lr) * 128;     // A-buf-relative; + mt*2048 + coff
    const int bB = (wn * 64 + lr) * 128;     // B-buf-relative; + nt*2048 + coff
    const int c0off = (lg * 16) ^ swz;
    const int c1off = (64 + lg * 16) ^ swz;

    f32x4 acc[4][4];
#pragma unroll
    for (int mt = 0; mt < 4; mt++)
#pragma unroll
        for (int nt = 0; nt < 4; nt++) acc[mt][nt] = (f32x4){0.f, 0.f, 0.f, 0.f};

#define GLL(srcp, dstoff) __builtin_amdgcn_global_load_lds(GLP(srcp), LDSP(smem + (dstoff)), 16, 0, 0)
#define STAGE_A(ak, ai) {                                                         \
    const char* as_ = Asrc + (ak) * 16384;                                        \
    const int ad_ = (ai) * 16384;                                                 \
    GLL(as_ + t * 16, ad_ + t * 16);                                              \
    GLL(as_ + 8192 + t * 16, ad_ + 8192 + t * 16); }
#define STAGE_B(bk, bi) {                                                         \
    const char* bs_ = Bsrc + (bk) * 32768;                                        \
    const int bd_ = 49152 + (bi) * 32768;                                         \
    GLL(bs_ + t * 16, bd_ + t * 16);                                              \
    GLL(bs_ + 8192 + t * 16, bd_ + 8192 + t * 16);                                \
    GLL(bs_ + 16384 + t * 16, bd_ + 16384 + t * 16);                              \
    GLL(bs_ + 24576 + t * 16, bd_ + 24576 + t * 16); }

    const int AK[12] = {0, 1, 2, 3, 0, 1, 2, 3, 4, 5, 6, 7};
    const int BKs[12] = {0, 1, 2, 3, 4, 5, 6, 7, 0, 1, 2, 3};

    // prologue: A(0), B(0), A(1)  -> entry-0 vmcnt(2) drains A0+B0, keeps A1
    STAGE_A(AK[0], 0);
    STAGE_B(BKs[0], 0);
    STAGE_A(AK[1], 1);

#pragma unroll
    for (int s = 0; s < 12; s++) {
        if (s < 11) asm volatile("s_waitcnt vmcnt(2)" ::: "memory");
        else        asm volatile("s_waitcnt vmcnt(0)" ::: "memory");
        __builtin_amdgcn_s_barrier();
        asm volatile("" ::: "memory");
        const char* Ab = smem + (s % 3) * 16384;
        const char* Bb = smem + 49152 + (s & 1) * 32768;
        short8v af[4], bf[4];

        // ---- phase 0: kk0 ----
#pragma unroll
        for (int mt = 0; mt < 4; mt++) af[mt] = *(const short8v*)(Ab + aB + mt * 2048 + c0off);
#pragma unroll
        for (int nt = 0; nt < 4; nt++) bf[nt] = *(const short8v*)(Bb + bB + nt * 2048 + c0off);
        if (s < 11) STAGE_B(BKs[s + 1], (s + 1) & 1);
        asm volatile("" ::: "memory");
        __builtin_amdgcn_s_barrier();
        asm volatile("s_waitcnt lgkmcnt(0)" ::: "memory");
        __builtin_amdgcn_sched_barrier(0);
        __builtin_amdgcn_s_setprio(1);
#pragma unroll
        for (int mt = 0; mt < 4; mt++)
#pragma unroll
            for (int nt = 0; nt < 4; nt++)
                acc[mt][nt] = __builtin_amdgcn_mfma_f32_16x16x32_bf16(af[mt], bf[nt], acc[mt][nt], 0, 0, 0);
        __builtin_amdgcn_s_setprio(0);
        asm volatile("" ::: "memory");
        __builtin_amdgcn_s_barrier();
        asm volatile("" ::: "memory");

        // ---- phase 1: kk1 ----
#pragma unroll
        for (int mt = 0; mt < 4; mt++) af[mt] = *(const short8v*)(Ab + aB + mt * 2048 + c1off);
#pragma unroll
        for (int nt = 0; nt < 4; nt++) bf[nt] = *(const short8v*)(Bb + bB + nt * 2048 + c1off);
        if (s < 10) STAGE_A(AK[s + 2], (s + 2) % 3);
        asm volatile("" ::: "memory");
        __builtin_amdgcn_s_barrier();
        asm volatile("s_waitcnt lgkmcnt(0)" ::: "memory");
        __builtin_amdgcn_sched_barrier(0);
        __builtin_amdgcn_s_setprio(1);
#pragma unroll
        for (int mt = 0; mt < 4; mt++)
#pragma unroll
            for (int nt = 0; nt < 4; nt++)
                acc[mt][nt] = __builtin_amdgcn_mfma_f32_16x16x32_bf16(af[mt], bf[nt], acc[mt][nt], 0, 0, 0);
        __builtin_amdgcn_s_setprio(0);
        // next iteration's entry barrier closes the step (all waves' phase-1 reads done)
    }
#undef STAGE_A
#undef STAGE_B
#undef GLL

    // epilogue (r7 verbatim): per-lane argmin over nt, 16-lane reduce, cross-wn via LDS
    float ne_v[4];
#pragma unroll
    for (int nt = 0; nt < 4; nt++) ne_v[nt] = normE[nblk * 256 + wn * 64 + nt * 16 + lr];

#pragma unroll
    for (int mt = 0; mt < 4; mt++) {
#pragma unroll
        for (int r = 0; r < 4; r++) {
            float m1 = __uint_as_float(0x7F7FFFFFu);   // FLT_MAX
            float m2 = m1;
            u32 col = 0;
#pragma unroll
            for (int nt = 0; nt < 4; nt++) {
                float f = fmaf(-2.0f, acc[mt][nt][r], ne_v[nt]);
                float mx = fmaxf(m1, f);
                m2 = fminf(m2, mx);
                bool p = f < m1;
                m1 = fminf(m1, f);
                u32 cg = (u32)(nblk * 256 + wn * 64 + nt * 16 + lr);
                col = p ? cg : col;
            }
            u64 key = ((u64)sortable(m1) << 32) | col;
#pragma unroll
            for (int off = 1; off < 16; off <<= 1) {
                u64 ko = __shfl_xor(key, off, 16);
                float m1o = __shfl_xor(m1, off, 16);
                float m2o = __shfl_xor(m2, off, 16);
                m2 = fminf(fminf(m2, m2o), fmaxf(m1, m1o));
                m1 = fminf(m1, m1o);
                key = umin64(key, ko);
            }
            if (lr == 0) {
                int slot = (wm * 64 + mt * 16 + lg * 4 + r) * 4 + wn;
                *(u64*)(smem + slot * 16) = key;
                *(float*)(smem + slot * 16 + 8) = m2;
            }
        }
    }
    __syncthreads();
    if (t < 128) {
        u64 k_i[4]; float m2_i[4];
#pragma unroll
        for (int i = 0; i < 4; i++) {
            k_i[i] = *(const u64*)(smem + (t * 4 + i) * 16);
            m2_i[i] = *(const float*)(smem + (t * 4 + i) * 16 + 8);
        }
        u64 K = umin64(umin64(k_i[0], k_i[1]), umin64(k_i[2], k_i[3]));
        float F2 = __uint_as_float(0x7F7FFFFFu);
#pragma unroll
        for (int i = 0; i < 4; i++) {
            float f1i = unsortable((u32)(k_i[i] >> 32));
            F2 = fminf(F2, (k_i[i] == K) ? m2_i[i] : f1i);
        }
        int rowg = mblk * 128 + t;
        gkey[(size_t)nblk * 32768 + rowg] = K;
        gm2[(size_t)nblk * 32768 + rowg] = F2;
    }
}

// ---- combine 4 nblk results -> idx + flag list ----
__global__ __launch_bounds__(512) void vq_combine(const u64* __restrict__ gkey, const float* __restrict__ gm2,
                                                  u32* __restrict__ idx_arr, u32* __restrict__ flaglist,
                                                  u32* __restrict__ cnt) {
    const int row = blockIdx.x * 512 + threadIdx.x;
    u64 k_i[4]; float m2_i[4];
#pragma unroll
    for (int n = 0; n < 4; n++) {
        k_i[n] = gkey[(size_t)n * 32768 + row];
        m2_i[n] = gm2[(size_t)n * 32768 + row];
    }
    u64 K = umin64(umin64(k_i[0], k_i[1]), umin64(k_i[2], k_i[3]));
    float F1 = unsortable((u32)(K >> 32));
    float F2 = __uint_as_float(0x7F7FFFFFu);
#pragma unroll
    for (int n = 0; n < 4; n++) {
        float f1i = unsortable((u32)(k_i[n] >> 32));
        F2 = fminf(F2, (k_i[n] == K) ? m2_i[n] : f1i);
    }
    idx_arr[row] = (u32)(K & 0xFFFFFFFFu);
    if (F2 - F1 < MARGIN) {
        u32 p = atomicAdd(cnt, 1u);
        flaglist[p] = (u32)row;
    }
}

// ---- exact fp32 recheck of flagged rows (bit-identical to verified round-2 math) ----
__global__ __launch_bounds__(512) void vq_recheck(const float* __restrict__ X, const float* __restrict__ E,
                                                  const float* __restrict__ normE,
                                                  const u32* __restrict__ flaglist, const u32* __restrict__ cnt,
                                                  u32* __restrict__ idx_arr) {
    __shared__ float xrow[256];
    __shared__ float r2part[32];
    __shared__ float r2s;
    __shared__ u64 wkey[8];
    const int t = threadIdx.x;
    const int n = (int)*cnt;
    for (int i = blockIdx.x; i < n; i += 256) {
        const int row = (int)flaglist[i];
        __syncthreads();
        if (t < 64) ((float4*)xrow)[t] = ((const float4*)(X + (size_t)row * 256))[t];
        __syncthreads();
        if (t < 32) {
            float s = 0.f;
#pragma unroll
            for (int k = 0; k < 8; k++) {
                float v = xrow[t * 8 + k];
                s = fmaf(v, v, s);
            }
            r2part[t] = s;
        }
        __syncthreads();
        if (t == 0) {
            float s = 0.f;
#pragma unroll
            for (int k = 0; k < 32; k++) s += r2part[k];
            r2s = s;
        }
        __syncthreads();
        const float r2 = r2s;
        const int c0 = t * 2;
        float ax = 0.f, ay = 0.f;
        for (int d = 0; d < 256; d += 4) {
#pragma unroll
            for (int dd = 0; dd < 4; dd++) {
                float xv = xrow[d + dd];
                float2 e = *(const float2*)(E + (d + dd) * NUM_EMB + c0);
                ax = fmaf(xv, e.x, ax);
                ay = fmaf(xv, e.y, ay);
            }
        }
        float2 ne = *(const float2*)(normE + c0);
        float f0 = (r2 + ne.x) - 2.0f * ax;
        float f1 = (r2 + ne.y) - 2.0f * ay;
        u64 k0 = ((u64)sortable(f0) << 32) | (u32)c0;
        u64 k1 = ((u64)sortable(f1) << 32) | (u32)(c0 + 1);
        u64 km = umin64(k0, k1);
#pragma unroll
        for (int off = 32; off; off >>= 1) km = umin64(km, __shfl_xor(km, off, 64));
        if ((t & 63) == 0) wkey[t >> 6] = km;
        __syncthreads();
        if (t == 0) {
            u64 m = wkey[0];
#pragma unroll
            for (int w2 = 1; w2 < 8; w2++) m = umin64(m, wkey[w2]);
            idx_arr[row] = (u32)(m & 0xFFFFFFFFull);
        }
    }
}

// ---- straight-through out + loss partials ----
__global__ __launch_bounds__(512) void vq_out(const float* __restrict__ X, const float* __restrict__ ET,
                                              const u32* __restrict__ idx_arr,
                                              float* __restrict__ out, float* __restrict__ partial) {
    __shared__ float lred[8];
    const int t = threadIdx.x;
    const long long base = (long long)blockIdx.x * 4096;   // 16 rows * 256
    const int dcol = t & 255, half = t >> 8;
    float lsum = 0.f;
#pragma unroll
    for (int rr = 0; rr < 8; rr++) {
        const int r = half * 8 + rr;
        const int row = blockIdx.x * 16 + r;
        const u32 idx = idx_arr[row];
        const float q = ET[(size_t)idx * EMB_DIM + dcol];
        const float x = X[base + r * EMB_DIM + dcol];
        out[base + r * EMB_DIM + dcol] = x + (q - x);
        const float df = x - q;
        lsum = fmaf(df, df, lsum);
    }
#pragma unroll
    for (int off = 32; off; off >>= 1) lsum += __shfl_down(lsum, off, 64);
    if ((t & 63) == 0) lred[t >> 6] = lsum;
    __syncthreads();
    if (t == 0) {
        float s = 0.f;
#pragma unroll
        for (int w = 0; w < 8; w++) s += lred[w];
        partial[blockIdx.x] = s;
    }
}

// ---- finish: loss = m + 0.25*m ----
__global__ void vq_finish(const float* __restrict__ partial, float* __restrict__ loss_out) {
    __shared__ float red[256];
    const int t = threadIdx.x;
    float s = 0.f;
    for (int i = t; i < 2048; i += 256) s += partial[i];
    red[t] = s;
    __syncthreads();
    for (int k = 128; k > 0; k >>= 1) {
        if (t < k) red[t] += red[t + k];
        __syncthreads();
    }
    if (t == 0) {
        const float m = red[0] / 8388608.0f;
        loss_out[0] = fmaf(0.25f, m, m);
    }
}

extern "C" void kernel_launch(void* const* d_in, const int* in_sizes, int n_in,
                              void* d_out, int out_size, void* d_ws, size_t ws_size,
                              hipStream_t stream) {
    const float* X = (const float*)d_in[0];      // (32,32,32,256) fp32
    const float* E = (const float*)d_in[1];      // (256,1024) fp32
    float* out = (float*)d_out;

    // workspace layout (bytes)
    char* ws = (char*)d_ws;
    float* ET       = (float*)(ws + 0);            // 1 MB
    float* normE    = (float*)(ws + 1048576);      // 4 KB
    float* partial  = (float*)(ws + 1052672);      // 8 KB
    char*  Es       = ws + 1060864;                // 1 MB
    u64*   gkey     = (u64*)(ws + 2109440);        // 1 MB
    float* gm2      = (float*)(ws + 3158016);      // 512 KB
    u32*   idx_arr  = (u32*)(ws + 3682304);        // 128 KB
    u32*   flaglist = (u32*)(ws + 3813376);        // 128 KB
    u32*   cnt      = (u32*)(ws + 3944448);        // 4 B

    // Xs (bf16 hi/lo, 32 MB) aliases d_out; fully consumed before vq_out overwrites.
    char* Xs = (char*)d_out;

    hipMemsetAsync(cnt, 0, 4, stream);
    vq_prep<<<354, 512, 0, stream>>>(X, E, ET, normE, Es, Xs);
    vq_gemm<<<1024, 512, 114688, stream>>>(Xs, Es, normE, gkey, gm2);
    vq_combine<<<64, 512, 0, stream>>>(gkey, gm2, idx_arr, flaglist, cnt);
    vq_recheck<<<256, 512, 0, stream>>>(X, E, normE, flaglist, cnt, idx_arr);
    vq_out<<<2048, 512, 0, stream>>>(X, ET, idx_arr, out, partial);
    vq_finish<<<1, 256, 0, stream>>>(partial, out + (out_size - 1));
}